// Round 5
// baseline (284.728 us; speedup 1.0000x reference)
//
#include <hip/hip_runtime.h>

// Problem constants (fixed by setup_inputs in the reference)
#define S_SPK 2
#define B_BATCH 4
#define M_MIC 4
#define W_TAP 3
#define F_FREQ 257
#define T_TIME 512
#define C_CH 4
#define FT (F_FREQ * T_TIME)      // 131584

// Mapping: wave -> (f, t-half). Lane l covers t = half*256 + 4l .. +3.
// Block = 256 threads = 4 waves = 2 f-rows x 2 halves.
// Grid = (129, 8). No LDS, no barriers; VGPR-lean (one (m,w) live at a time).

typedef float floatx4 __attribute__((ext_vector_type(4)));

__global__ void zero_ws_kernel(float* ws) {
    if (threadIdx.x < 16) ws[threadIdx.x] = 0.0f;
}

__device__ __forceinline__ floatx4 nt_load4(const float* p) {
    return __builtin_nontemporal_load((const floatx4*)p);
}

__global__ __launch_bounds__(256) void pit_main_kernel(
    const float* __restrict__ masks,   // [S,B,M,W,F,T,2]
    const float* __restrict__ mixr,    // [S,B,M,F,T]
    const float* __restrict__ mixi,    // [S,B,M,F,T]
    const float* __restrict__ tgtr,    // [S,B,C,F,T] (use c=0)
    const float* __restrict__ tgti,    // [S,B,C,F,T]
    float* __restrict__ ws)
{
    const int sb   = blockIdx.y;             // so*B + b
    const int so   = sb / B_BATCH;
    const int b    = sb % B_BATCH;
    const int wave = threadIdx.x >> 6;
    const int lane = threadIdx.x & 63;
    const int f    = blockIdx.x * 2 + (wave >> 1);
    const int t0   = (wave & 1) * 256 + lane * 4;   // this thread: t0..t0+3

    float L0 = 0.0f, L1 = 0.0f;

    if (f < F_FREQ) {
        float orr[4] = {0.f, 0.f, 0.f, 0.f};
        float oii[4] = {0.f, 0.f, 0.f, 0.f};

        const int ft      = f * T_TIME + t0;
        const int mixBase = sb * M_MIC * FT + ft;
        const int mskBase = (sb * M_MIC * W_TAP) * (FT * 2) + ft * 2;
        const bool lo_ok  = (t0 > 0);
        const bool hi_ok  = (t0 + 4 < T_TIME);

        #pragma unroll 1
        for (int m = 0; m < M_MIC; ++m) {
            const float* mrp = mixr + mixBase + m * FT;   // points at t0
            const float* mip = mixi + mixBase + m * FT;

            // window win[k] = mix[t0 + k - 1], k = 0..5
            float wr[6], wi[6];
            {
                const float4 r4 = *(const float4*)mrp;
                const float4 i4 = *(const float4*)mip;
                wr[0] = lo_ok ? mrp[-1] : 0.0f;
                wi[0] = lo_ok ? mip[-1] : 0.0f;
                wr[1] = r4.x; wr[2] = r4.y; wr[3] = r4.z; wr[4] = r4.w;
                wi[1] = i4.x; wi[2] = i4.y; wi[3] = i4.z; wi[4] = i4.w;
                wr[5] = hi_ok ? mrp[4] : 0.0f;
                wi[5] = hi_ok ? mip[4] : 0.0f;
            }

            const int mB = mskBase + (m * W_TAP) * (FT * 2);
            #pragma unroll
            for (int w = 0; w < W_TAP; ++w) {
                // masks[sb,m,w,f,t0..t0+3,re/im] -> two nt float4 (32 B)
                const float* mp = masks + mB + w * (FT * 2);
                const floatx4 f0 = nt_load4(mp);
                const floatx4 f1 = nt_load4(mp + 4);
                // out[j] += win[j+w] * filt[j]   (complex)
                orr[0] += wr[w]     * f0.x - wi[w]     * f0.y;
                oii[0] += wr[w]     * f0.y + wi[w]     * f0.x;
                orr[1] += wr[w + 1] * f0.z - wi[w + 1] * f0.w;
                oii[1] += wr[w + 1] * f0.w + wi[w + 1] * f0.z;
                orr[2] += wr[w + 2] * f1.x - wi[w + 2] * f1.y;
                oii[2] += wr[w + 2] * f1.y + wi[w + 2] * f1.x;
                orr[3] += wr[w + 3] * f1.z - wi[w + 3] * f1.w;
                oii[3] += wr[w + 3] * f1.w + wi[w + 3] * f1.z;
            }
        }

        // targets, channel 0, both candidate speakers st = 0,1
        #pragma unroll
        for (int st = 0; st < S_SPK; ++st) {
            const int tB = (st * B_BATCH + b) * C_CH * FT + ft;
            const float4 tr = *(const float4*)(tgtr + tB);
            const float4 ti = *(const float4*)(tgti + tB);
            const float trj[4] = {tr.x, tr.y, tr.z, tr.w};
            const float tij[4] = {ti.x, ti.y, ti.z, ti.w};
            float acc = 0.0f;
            #pragma unroll
            for (int j = 0; j < 4; ++j) {
                const float ao = sqrtf(orr[j] * orr[j] + oii[j] * oii[j]);
                const float at = sqrtf(trj[j] * trj[j] + tij[j] * tij[j]);
                acc += fabsf(trj[j] - orr[j]) + fabsf(tij[j] - oii[j]) + fabsf(at - ao);
            }
            if (st == 0) L0 = acc; else L1 = acc;
        }
    }

    // wave(64) shuffle reduction; 2 atomics per wave, no LDS/barrier
    #pragma unroll
    for (int off = 32; off > 0; off >>= 1) {
        L0 += __shfl_down(L0, off, 64);
        L1 += __shfl_down(L1, off, 64);
    }
    if (lane == 0 && f < F_FREQ) {
        atomicAdd(&ws[(so * S_SPK + 0) * B_BATCH + b], L0);
        atomicAdd(&ws[(so * S_SPK + 1) * B_BATCH + b], L1);
    }
}

__global__ void pit_final_kernel(const float* __restrict__ ws,
                                 float* __restrict__ out, int num_utts) {
    if (threadIdx.x == 0 && blockIdx.x == 0) {
        float acc = 0.0f;
        for (int b = 0; b < B_BATCH; ++b) {
            // perm (0,1): L[0][0] + L[1][1];  perm (1,0): L[0][1] + L[1][0]
            const float pid = ws[(0 * S_SPK + 0) * B_BATCH + b] + ws[(1 * S_SPK + 1) * B_BATCH + b];
            const float psw = ws[(0 * S_SPK + 1) * B_BATCH + b] + ws[(1 * S_SPK + 0) * B_BATCH + b];
            const float sc0 = 3.0f * pid / (float)S_SPK;
            const float sc1 = 3.0f * psw / (float)S_SPK;
            acc += fminf(sc0, sc1);
        }
        out[0] = acc / (float)num_utts;
    }
}

extern "C" void kernel_launch(void* const* d_in, const int* in_sizes, int n_in,
                              void* d_out, int out_size, void* d_ws, size_t ws_size,
                              hipStream_t stream) {
    const float* masks = (const float*)d_in[0];
    const float* mixr  = (const float*)d_in[1];
    const float* mixi  = (const float*)d_in[2];
    const float* tgtr  = (const float*)d_in[3];
    const float* tgti  = (const float*)d_in[4];
    // input_sizes values are never used by the reference; only its length is.
    const int num_utts = in_sizes[5];

    float* ws  = (float*)d_ws;
    float* out = (float*)d_out;

    zero_ws_kernel<<<1, 64, 0, stream>>>(ws);

    dim3 grid((F_FREQ + 1) / 2, S_SPK * B_BATCH);   // (129, 8)
    pit_main_kernel<<<grid, 256, 0, stream>>>(masks, mixr, mixi, tgtr, tgti, ws);

    pit_final_kernel<<<1, 64, 0, stream>>>(ws, out, num_utts);
}